// Round 1
// baseline (2549.388 us; speedup 1.0000x reference)
//
#include <hip/hip_runtime.h>
#include <hip/hip_bf16.h>

#define HW 65536
#define IMG 256
static constexpr int CDIM = 192;

// ---------------- GEMM: Y[o,p] = sum_c A[o,c] * X[c,p] (+ bias[o]) ----------
// A: [M,192] row-major. X: [192, HW] row-major (row stride HW). Y: [M, HW].
// grid: (HW/64, M/64), block 256. BK=32, thread tile 4x4.
__global__ void gemm_conv1x1(const float* __restrict__ A,
                             const float* __restrict__ X,
                             const float* __restrict__ bias,
                             float* __restrict__ Y) {
    __shared__ float As[32][68];
    __shared__ float Bs[32][64];
    const int tid = threadIdx.x;
    const int tx = tid & 15, ty = tid >> 4;
    const int mBase = blockIdx.y * 64;
    const int nBase = blockIdx.x * 64;

    float acc[4][4];
#pragma unroll
    for (int i = 0; i < 4; i++)
#pragma unroll
        for (int j = 0; j < 4; j++) acc[i][j] = 0.f;

    for (int k0 = 0; k0 < 192; k0 += 32) {
        // A tile: 64 rows x 32 cols = 512 float4, transposed into As[k][m]
#pragma unroll
        for (int l = 0; l < 2; l++) {
            int idx = tid + l * 256;
            int row = idx >> 3, c4 = idx & 7;
            float4 av = *(const float4*)(A + (size_t)(mBase + row) * 192 + k0 + c4 * 4);
            As[c4 * 4 + 0][row] = av.x;
            As[c4 * 4 + 1][row] = av.y;
            As[c4 * 4 + 2][row] = av.z;
            As[c4 * 4 + 3][row] = av.w;
        }
        // B tile: 32 rows x 64 cols
#pragma unroll
        for (int l = 0; l < 2; l++) {
            int idx = tid + l * 256;
            int row = idx >> 4, c4 = idx & 15;
            float4 bv = *(const float4*)(X + (size_t)(k0 + row) * HW + nBase + c4 * 4);
            *(float4*)&Bs[row][c4 * 4] = bv;
        }
        __syncthreads();
#pragma unroll
        for (int kk = 0; kk < 32; kk++) {
            float4 a4 = *(const float4*)&As[kk][ty * 4];
            float4 b4 = *(const float4*)&Bs[kk][tx * 4];
            acc[0][0] += a4.x * b4.x; acc[0][1] += a4.x * b4.y; acc[0][2] += a4.x * b4.z; acc[0][3] += a4.x * b4.w;
            acc[1][0] += a4.y * b4.x; acc[1][1] += a4.y * b4.y; acc[1][2] += a4.y * b4.z; acc[1][3] += a4.y * b4.w;
            acc[2][0] += a4.z * b4.x; acc[2][1] += a4.z * b4.y; acc[2][2] += a4.z * b4.z; acc[2][3] += a4.z * b4.w;
            acc[3][0] += a4.w * b4.x; acc[3][1] += a4.w * b4.y; acc[3][2] += a4.w * b4.z; acc[3][3] += a4.w * b4.w;
        }
        __syncthreads();
    }
#pragma unroll
    for (int i = 0; i < 4; i++) {
        float bv = bias ? bias[mBase + ty * 4 + i] : 0.f;
        float4 o4 = make_float4(acc[i][0] + bv, acc[i][1] + bv, acc[i][2] + bv, acc[i][3] + bv);
        *(float4*)(Y + (size_t)(mBase + ty * 4 + i) * HW + nBase + tx * 4) = o4;
    }
}

// ---------------- Depthwise conv (radius R), zero pad, + bias ---------------
// grid: (64 tiles of 32x32, C), block 256, 4 px/thread.
template <int R>
__global__ void dwconv_kernel(const float* __restrict__ in,
                              const float* __restrict__ wdw,
                              const float* __restrict__ bias,
                              float* __restrict__ out) {
    constexpr int KS = 2 * R + 1;
    constexpr int LW = 32 + 2 * R;
    __shared__ float tile[LW * LW];
    const int c = blockIdx.y;
    const int t = blockIdx.x;
    const int ty0 = (t >> 3) * 32, tx0 = (t & 7) * 32;
    const float* src = in + (size_t)c * HW;

    float wreg[KS * KS];
#pragma unroll
    for (int i = 0; i < KS * KS; i++) wreg[i] = wdw[c * KS * KS + i];
    const float bval = bias[c];

    for (int idx = threadIdx.x; idx < LW * LW; idx += 256) {
        int ly = idx / LW, lx = idx - ly * LW;
        int gy = ty0 + ly - R, gx = tx0 + lx - R;
        float v = 0.f;
        if (gy >= 0 && gy < IMG && gx >= 0 && gx < IMG) v = src[gy * IMG + gx];
        tile[idx] = v;
    }
    __syncthreads();

#pragma unroll
    for (int kp = 0; kp < 4; kp++) {
        int idx = threadIdx.x + kp * 256;
        int py = idx >> 5, px = idx & 31;
        float acc = bval;
#pragma unroll
        for (int ky = 0; ky < KS; ky++)
#pragma unroll
            for (int kx = 0; kx < KS; kx++)
                acc += tile[(py + ky) * LW + (px + kx)] * wreg[ky * KS + kx];
        out[(size_t)c * HW + (ty0 + py) * IMG + tx0 + px] = acc;
    }
}

// ------------- Per-patch 8x8 circular convolution (the FFT part) ------------
// out[i,j] = sum_{a,b} q[a,b] * k[(i-a)%8,(j-b)%8]; one lane per (c,patch).
// grid: 192*1024/256 = 768 blocks, block 256.
__global__ void circconv_kernel(const float* __restrict__ q,
                                const float* __restrict__ kin,
                                float* __restrict__ out) {
    const int g = blockIdx.x * 256 + threadIdx.x;
    const int c = g >> 10;
    const int patch = g & 1023;
    const int ph = patch >> 5, pw = patch & 31;
    const size_t base = (size_t)c * HW + (size_t)(ph * 8) * IMG + pw * 8;
    const float* qb = q + base;
    const float* kb = kin + base;

    float qv[8][8], kv[8][8];
#pragma unroll
    for (int a = 0; a < 8; a++) {
        float4 lo = *(const float4*)(qb + a * IMG);
        float4 hi = *(const float4*)(qb + a * IMG + 4);
        qv[a][0] = lo.x; qv[a][1] = lo.y; qv[a][2] = lo.z; qv[a][3] = lo.w;
        qv[a][4] = hi.x; qv[a][5] = hi.y; qv[a][6] = hi.z; qv[a][7] = hi.w;
        float4 klo = *(const float4*)(kb + a * IMG);
        float4 khi = *(const float4*)(kb + a * IMG + 4);
        kv[a][0] = klo.x; kv[a][1] = klo.y; kv[a][2] = klo.z; kv[a][3] = klo.w;
        kv[a][4] = khi.x; kv[a][5] = khi.y; kv[a][6] = khi.z; kv[a][7] = khi.w;
    }

    float* ob = out + base;
#pragma unroll
    for (int i = 0; i < 8; i++) {
        float o[8];
#pragma unroll
        for (int j = 0; j < 8; j++) {
            float acc = 0.f;
#pragma unroll
            for (int a = 0; a < 8; a++)
#pragma unroll
                for (int b = 0; b < 8; b++)
                    acc += qv[a][b] * kv[(i - a + 8) & 7][(j - b + 8) & 7];
            o[j] = acc;
        }
        *(float4*)(ob + i * IMG) = make_float4(o[0], o[1], o[2], o[3]);
        *(float4*)(ob + i * IMG + 4) = make_float4(o[4], o[5], o[6], o[7]);
    }
}

// ------------- LayerNorm over channels + affine + multiply by v -------------
// grid: HW/256 blocks, block 256. One thread per pixel.
__global__ void ln_mul_kernel(const float* __restrict__ s,
                              const float* __restrict__ v,
                              const float* __restrict__ ln_w,
                              const float* __restrict__ ln_b,
                              float* __restrict__ y) {
    const int p = blockIdx.x * 256 + threadIdx.x;
    float sum = 0.f, sumsq = 0.f;
    for (int c = 0; c < CDIM; c++) {
        float val = s[(size_t)c * HW + p];
        sum += val;
        sumsq += val * val;
    }
    const float mean = sum * (1.f / CDIM);
    const float var = sumsq * (1.f / CDIM) - mean * mean;
    const float rstd = rsqrtf(var + 1e-5f);
    for (int c = 0; c < CDIM; c++) {
        float val = s[(size_t)c * HW + p];
        float nr = (val - mean) * rstd * ln_w[c] + ln_b[c];
        y[(size_t)c * HW + p] = nr * v[(size_t)c * HW + p];
    }
}

extern "C" void kernel_launch(void* const* d_in, const int* in_sizes, int n_in,
                              void* d_out, int out_size, void* d_ws, size_t ws_size,
                              hipStream_t stream) {
    const float* x      = (const float*)d_in[0];
    const float* wq     = (const float*)d_in[1];
    const float* w_qdw  = (const float*)d_in[2];
    const float* b_qdw  = (const float*)d_in[3];
    const float* wkv    = (const float*)d_in[4];
    const float* w_kvdw = (const float*)d_in[5];
    const float* b_kvdw = (const float*)d_in[6];
    const float* ln_w   = (const float*)d_in[7];
    const float* ln_b   = (const float*)d_in[8];
    const float* w_proj = (const float*)d_in[9];
    const float* b_proj = (const float*)d_in[10];
    float* out = (float*)d_out;
    float* ws  = (float*)d_ws;

    // ws regions (floats): q0 [192*HW], kv0 [384*HW], q [192*HW], kv [384*HW]
    float* q0    = ws;                              // also reused for circconv out
    float* kv0   = ws + (size_t)12582912;           // also reused for LN*v out
    float* qbuf  = ws + (size_t)37748736;
    float* kvbuf = ws + (size_t)50331648;           // k = first 192 ch, v = last 192

    for (int b = 0; b < 4; b++) {
        const float* xb = x + (size_t)b * CDIM * HW;
        // 1x1 convs (GEMMs)
        gemm_conv1x1<<<dim3(HW / 64, 3), 256, 0, stream>>>(wq, xb, nullptr, q0);
        gemm_conv1x1<<<dim3(HW / 64, 6), 256, 0, stream>>>(wkv, xb, nullptr, kv0);
        // depthwise convs
        dwconv_kernel<1><<<dim3(64, 192), 256, 0, stream>>>(q0, w_qdw, b_qdw, qbuf);
        dwconv_kernel<3><<<dim3(64, 384), 256, 0, stream>>>(kv0, w_kvdw, b_kvdw, kvbuf);
        // per-patch circular convolution (FFT part); k = kvbuf first 192 channels
        circconv_kernel<<<768, 256, 0, stream>>>(qbuf, kvbuf, q0);
        // LayerNorm over channels, affine, * v
        ln_mul_kernel<<<HW / 256, 256, 0, stream>>>(q0, kvbuf + (size_t)192 * HW,
                                                    ln_w, ln_b, kv0);
        // output projection (GEMM + bias)
        gemm_conv1x1<<<dim3(HW / 64, 3), 256, 0, stream>>>(w_proj, kv0, b_proj,
                                                           out + (size_t)b * CDIM * HW);
    }
}

// Round 2
// 1365.127 us; speedup vs baseline: 1.8675x; 1.8675x over previous
//
#include <hip/hip_runtime.h>
#include <hip/hip_bf16.h>

#define HW 65536
#define IMG 256
static constexpr int CDIM = 192;

typedef __attribute__((ext_vector_type(8))) short short8;
typedef __attribute__((ext_vector_type(4))) float f32x4;

// ---------------- pack weights fp32 -> bf16 ---------------------------------
// Wqkv rows 0..191 = wq, rows 192..575 = wkv (both [o][c] row-major, contiguous)
__global__ void pack_weights(const float* __restrict__ wq,
                             const float* __restrict__ wkv,
                             const float* __restrict__ wp,
                             __hip_bfloat16* __restrict__ Wqkv,
                             __hip_bfloat16* __restrict__ Wp) {
    int i = blockIdx.x * 256 + threadIdx.x;
    if (i < 36864) Wqkv[i] = __float2bfloat16(wq[i]);
    else if (i < 110592) Wqkv[i] = __float2bfloat16(wkv[i - 36864]);
    else if (i < 147456) Wp[i - 110592] = __float2bfloat16(wp[i - 110592]);
}

// ---------------- transpose + convert: x[c][p] f32 -> xT[p][c] bf16 ---------
// grid (HW/32, 192/32), block 256 (=32x8)
__global__ void transpose_cvt(const float* __restrict__ x,
                              __hip_bfloat16* __restrict__ xT) {
    __shared__ float tile[32][33];
    const int p0 = blockIdx.x * 32, c0 = blockIdx.y * 32;
    const int tx = threadIdx.x & 31, ty = threadIdx.x >> 5;
#pragma unroll
    for (int r = 0; r < 4; r++)
        tile[ty + r * 8][tx] = x[(size_t)(c0 + ty + r * 8) * HW + p0 + tx];
    __syncthreads();
#pragma unroll
    for (int r = 0; r < 4; r++)
        xT[(size_t)(p0 + ty + r * 8) * 192 + c0 + tx] =
            __float2bfloat16(tile[tx][ty + r * 8]);
}

// ---------------- MFMA GEMM: Y[m][n] = sum_k A[m][k] * Bt[n][k] (+bias[m]) --
// A [M][192] bf16, Bt [HW][192] bf16, Y [M][HW] fp32.
// grid (M/64, HW/128), block 256 = 4 waves; wave w owns rows w*16..w*16+15.
__global__ void gemm_bf16(const __hip_bfloat16* __restrict__ A,
                          const __hip_bfloat16* __restrict__ Bt,
                          const float* __restrict__ bias,
                          float* __restrict__ Y) {
    __shared__ short As[64][200];   // pad 192->200 (+16B) -> 2-way banks (free)
    __shared__ short Bs[128][200];
    const int tid = threadIdx.x;
    const int wid = tid >> 6, lane = tid & 63;
    const int mBase = blockIdx.x * 64, nBase = blockIdx.y * 128;

    // stage A: 64 rows x 24 chunks of 8 bf16 = 1536 chunks, 6/thread
#pragma unroll
    for (int l = 0; l < 6; l++) {
        int ch = tid + l * 256;
        int row = ch / 24, cc = ch % 24;
        short8 v = *(const short8*)(A + (size_t)(mBase + row) * 192 + cc * 8);
        *(short8*)&As[row][cc * 8] = v;
    }
    // stage B: 128 rows x 24 chunks = 3072 chunks, 12/thread
#pragma unroll
    for (int l = 0; l < 12; l++) {
        int ch = tid + l * 256;
        int row = ch / 24, cc = ch % 24;
        short8 v = *(const short8*)(Bt + (size_t)(nBase + row) * 192 + cc * 8);
        *(short8*)&Bs[row][cc * 8] = v;
    }
    __syncthreads();

    const int lr = lane & 15, lg = lane >> 4;
    f32x4 acc[8];
#pragma unroll
    for (int f = 0; f < 8; f++) acc[f] = (f32x4){0.f, 0.f, 0.f, 0.f};

#pragma unroll
    for (int ks = 0; ks < 6; ks++) {
        short8 af = *(const short8*)&As[wid * 16 + lr][ks * 32 + lg * 8];
#pragma unroll
        for (int f = 0; f < 8; f++) {
            short8 bfr = *(const short8*)&Bs[f * 16 + lr][ks * 32 + lg * 8];
            acc[f] = __builtin_amdgcn_mfma_f32_16x16x32_bf16(af, bfr, acc[f], 0, 0, 0);
        }
    }

    const int mrow = mBase + wid * 16 + lg * 4;
#pragma unroll
    for (int f = 0; f < 8; f++) {
        int n = nBase + f * 16 + lr;
#pragma unroll
        for (int r = 0; r < 4; r++) {
            float bv = bias ? bias[mrow + r] : 0.f;
            Y[(size_t)(mrow + r) * HW + n] = acc[f][r] + bv;
        }
    }
}

// ---------------- Depthwise conv (radius R), zero pad, + bias ---------------
template <int R>
__global__ void dwconv_kernel(const float* __restrict__ in,
                              const float* __restrict__ wdw,
                              const float* __restrict__ bias,
                              float* __restrict__ out) {
    constexpr int KS = 2 * R + 1;
    constexpr int LW = 32 + 2 * R;
    __shared__ float tile[LW * LW];
    const int c = blockIdx.y;
    const int t = blockIdx.x;
    const int ty0 = (t >> 3) * 32, tx0 = (t & 7) * 32;
    const float* src = in + (size_t)c * HW;

    float wreg[KS * KS];
#pragma unroll
    for (int i = 0; i < KS * KS; i++) wreg[i] = wdw[c * KS * KS + i];
    const float bval = bias[c];

    for (int idx = threadIdx.x; idx < LW * LW; idx += 256) {
        int ly = idx / LW, lx = idx - ly * LW;
        int gy = ty0 + ly - R, gx = tx0 + lx - R;
        float v = 0.f;
        if (gy >= 0 && gy < IMG && gx >= 0 && gx < IMG) v = src[gy * IMG + gx];
        tile[idx] = v;
    }
    __syncthreads();

#pragma unroll
    for (int kp = 0; kp < 4; kp++) {
        int idx = threadIdx.x + kp * 256;
        int py = idx >> 5, px = idx & 31;
        float acc = bval;
#pragma unroll
        for (int ky = 0; ky < KS; ky++)
#pragma unroll
            for (int kx = 0; kx < KS; kx++)
                acc += tile[(py + ky) * LW + (px + kx)] * wreg[ky * KS + kx];
        out[(size_t)c * HW + (ty0 + py) * IMG + tx0 + px] = acc;
    }
}

// ------------- Per-patch 8x8 circular convolution ---------------------------
// lane = (i = tid>>5, pw = tid&31); block = (ph, c). ~30 live floats/lane.
__global__ void circconv2(const float* __restrict__ q,
                          const float* __restrict__ kin,
                          float* __restrict__ out) {
    const int c = blockIdx.y;
    const int ph = blockIdx.x;
    const int pw = threadIdx.x & 31;
    const int i = threadIdx.x >> 5;
    const size_t base = (size_t)c * HW + (size_t)(ph * 8) * IMG + pw * 8;

    float acc[8];
#pragma unroll
    for (int j = 0; j < 8; j++) acc[j] = 0.f;

#pragma unroll
    for (int a = 0; a < 8; a++) {
        const float* qr = q + base + a * IMG;
        const float* kr = kin + base + ((i - a + 8) & 7) * IMG;
        float4 q0 = *(const float4*)qr, q1 = *(const float4*)(qr + 4);
        float4 k0 = *(const float4*)kr, k1 = *(const float4*)(kr + 4);
        float qv[8] = {q0.x, q0.y, q0.z, q0.w, q1.x, q1.y, q1.z, q1.w};
        float kv[8] = {k0.x, k0.y, k0.z, k0.w, k1.x, k1.y, k1.z, k1.w};
#pragma unroll
        for (int b = 0; b < 8; b++)
#pragma unroll
            for (int j = 0; j < 8; j++)
                acc[j] += qv[b] * kv[(j - b + 8) & 7];
    }
    float* ob = out + base + (size_t)i * IMG;
    *(float4*)ob = make_float4(acc[0], acc[1], acc[2], acc[3]);
    *(float4*)(ob + 4) = make_float4(acc[4], acc[5], acc[6], acc[7]);
}

// ------------- LayerNorm(ch) + affine + *v, output bf16 transposed [p][c] ---
__global__ void ln_mul_bf16T(const float* __restrict__ s,
                             const float* __restrict__ v,
                             const float* __restrict__ ln_w,
                             const float* __restrict__ ln_b,
                             __hip_bfloat16* __restrict__ y) {
    const int p = blockIdx.x * 256 + threadIdx.x;
    float sum = 0.f, sumsq = 0.f;
    for (int c = 0; c < CDIM; c++) {
        float val = s[(size_t)c * HW + p];
        sum += val;
        sumsq += val * val;
    }
    const float mean = sum * (1.f / CDIM);
    const float var = sumsq * (1.f / CDIM) - mean * mean;
    const float rstd = rsqrtf(var + 1e-5f);
    for (int c0 = 0; c0 < CDIM; c0 += 8) {
        union { __hip_bfloat16 h[8]; short8 s8; } ob;
#pragma unroll
        for (int e = 0; e < 8; e++) {
            int c = c0 + e;
            float val = s[(size_t)c * HW + p];
            float nr = (val - mean) * rstd * ln_w[c] + ln_b[c];
            ob.h[e] = __float2bfloat16(nr * v[(size_t)c * HW + p]);
        }
        *(short8*)(y + (size_t)p * 192 + c0) = ob.s8;
    }
}

extern "C" void kernel_launch(void* const* d_in, const int* in_sizes, int n_in,
                              void* d_out, int out_size, void* d_ws, size_t ws_size,
                              hipStream_t stream) {
    const float* x      = (const float*)d_in[0];
    const float* wq     = (const float*)d_in[1];
    const float* w_qdw  = (const float*)d_in[2];
    const float* b_qdw  = (const float*)d_in[3];
    const float* wkv    = (const float*)d_in[4];
    const float* w_kvdw = (const float*)d_in[5];
    const float* b_kvdw = (const float*)d_in[6];
    const float* ln_w   = (const float*)d_in[7];
    const float* ln_b   = (const float*)d_in[8];
    const float* w_proj = (const float*)d_in[9];
    const float* b_proj = (const float*)d_in[10];
    float* out = (float*)d_out;
    float* ws  = (float*)d_ws;

    // ws map (f32 units), total ~302.3 MB:
    //   qkv0  [576*HW]  @ 0          (q0 = rows 0..191; kv0 = rows 192..575)
    //   qbuf  [192*HW]  @ 37748736   (dw-q out; later reused as lnT bf16)
    //   kvbuf [384*HW]  @ 50331648   (dw-kv out; k rows 0..191, v rows 192..383)
    //   xT    bf16, aliases kvbuf start (consumed before kvbuf written)
    //   Wqkv/Wp bf16 @ 75497472
    float* qkv0  = ws;
    float* qbuf  = ws + (size_t)37748736;
    float* kvbuf = ws + (size_t)50331648;
    __hip_bfloat16* xT   = (__hip_bfloat16*)(ws + (size_t)50331648);
    __hip_bfloat16* lnT  = (__hip_bfloat16*)(ws + (size_t)37748736);
    __hip_bfloat16* Wqkv = (__hip_bfloat16*)(ws + (size_t)75497472);
    __hip_bfloat16* Wp   = Wqkv + 110592;

    pack_weights<<<576, 256, 0, stream>>>(wq, wkv, w_proj, Wqkv, Wp);

    for (int b = 0; b < 4; b++) {
        const float* xb = x + (size_t)b * CDIM * HW;
        // x -> xT bf16 (xT aliases kvbuf; consumed by the next kernel only)
        transpose_cvt<<<dim3(HW / 32, 6), 256, 0, stream>>>(xb, xT);
        // fused q+kv 1x1 conv: [576,192] x [192,HW] via MFMA
        gemm_bf16<<<dim3(9, HW / 128), 256, 0, stream>>>(Wqkv, xT, nullptr, qkv0);
        // depthwise convs (fp32)
        dwconv_kernel<1><<<dim3(64, 192), 256, 0, stream>>>(qkv0, w_qdw, b_qdw, qbuf);
        dwconv_kernel<3><<<dim3(64, 384), 256, 0, stream>>>(qkv0 + (size_t)192 * HW,
                                                            w_kvdw, b_kvdw, kvbuf);
        // per-patch circular convolution -> overwrite qkv0 rows 0..191
        circconv2<<<dim3(32, 192), 256, 0, stream>>>(qbuf, kvbuf, qkv0);
        // LN over channels + *v, emit bf16 transposed [p][c] into lnT
        ln_mul_bf16T<<<HW / 256, 256, 0, stream>>>(qkv0, kvbuf + (size_t)192 * HW,
                                                   ln_w, ln_b, lnT);
        // output projection via MFMA (+bias)
        gemm_bf16<<<dim3(3, HW / 128), 256, 0, stream>>>(Wp, lnT, b_proj,
                                                         out + (size_t)b * CDIM * HW);
    }
}

// Round 3
// 843.270 us; speedup vs baseline: 3.0232x; 1.6188x over previous
//
#include <hip/hip_runtime.h>
#include <hip/hip_bf16.h>

#define HW 65536
#define IMG 256
static constexpr int CDIM = 192;

typedef __attribute__((ext_vector_type(8))) short short8;
typedef __attribute__((ext_vector_type(4))) float f32x4;

static __device__ __forceinline__ float b2f(unsigned short u) {
    union { unsigned u; float f; } t; t.u = ((unsigned)u) << 16; return t.f;
}
static __device__ __forceinline__ unsigned short f2bu(float f) {
    __hip_bfloat16 h = __float2bfloat16(f);
    return *reinterpret_cast<unsigned short*>(&h);
}

// ---------------- pack weights fp32 -> bf16 ---------------------------------
__global__ void pack_weights(const float* __restrict__ wq,
                             const float* __restrict__ wkv,
                             const float* __restrict__ wp,
                             __hip_bfloat16* __restrict__ Wqkv,
                             __hip_bfloat16* __restrict__ Wp) {
    int i = blockIdx.x * 256 + threadIdx.x;
    if (i < 36864) Wqkv[i] = __float2bfloat16(wq[i]);
    else if (i < 110592) Wqkv[i] = __float2bfloat16(wkv[i - 36864]);
    else if (i < 147456) Wp[i - 110592] = __float2bfloat16(wp[i - 110592]);
}

// ---------------- transpose + convert: x[c][p] f32 -> xT[p][c] bf16 ---------
__global__ void transpose_cvt(const float* __restrict__ x,
                              __hip_bfloat16* __restrict__ xT) {
    __shared__ float tile[32][33];
    const int p0 = blockIdx.x * 32, c0 = blockIdx.y * 32;
    const int tx = threadIdx.x & 31, ty = threadIdx.x >> 5;
#pragma unroll
    for (int r = 0; r < 4; r++)
        tile[ty + r * 8][tx] = x[(size_t)(c0 + ty + r * 8) * HW + p0 + tx];
    __syncthreads();
#pragma unroll
    for (int r = 0; r < 4; r++)
        xT[(size_t)(p0 + ty + r * 8) * 192 + c0 + tx] =
            __float2bfloat16(tile[tx][ty + r * 8]);
}

// ---------------- MFMA GEMM: Y[m][n] = sum_k A[m][k]*Bt[n][k], bf16 out -----
// A [M][192] bf16, Bt [HW][192] bf16, Y [M][HW] bf16.
// grid (M/64, HW/128), block 256 = 4 waves.
__global__ void gemm_bf16(const __hip_bfloat16* __restrict__ A,
                          const __hip_bfloat16* __restrict__ Bt,
                          __hip_bfloat16* __restrict__ Y) {
    __shared__ short As[64][200];
    __shared__ short Bs[128][200];
    const int tid = threadIdx.x;
    const int wid = tid >> 6, lane = tid & 63;
    const int mBase = blockIdx.x * 64, nBase = blockIdx.y * 128;

#pragma unroll
    for (int l = 0; l < 6; l++) {
        int ch = tid + l * 256;
        int row = ch / 24, cc = ch % 24;
        short8 v = *(const short8*)(A + (size_t)(mBase + row) * 192 + cc * 8);
        *(short8*)&As[row][cc * 8] = v;
    }
#pragma unroll
    for (int l = 0; l < 12; l++) {
        int ch = tid + l * 256;
        int row = ch / 24, cc = ch % 24;
        short8 v = *(const short8*)(Bt + (size_t)(nBase + row) * 192 + cc * 8);
        *(short8*)&Bs[row][cc * 8] = v;
    }
    __syncthreads();

    const int lr = lane & 15, lg = lane >> 4;
    f32x4 acc[8];
#pragma unroll
    for (int f = 0; f < 8; f++) acc[f] = (f32x4){0.f, 0.f, 0.f, 0.f};

#pragma unroll
    for (int ks = 0; ks < 6; ks++) {
        short8 af = *(const short8*)&As[wid * 16 + lr][ks * 32 + lg * 8];
#pragma unroll
        for (int f = 0; f < 8; f++) {
            short8 bfr = *(const short8*)&Bs[f * 16 + lr][ks * 32 + lg * 8];
            acc[f] = __builtin_amdgcn_mfma_f32_16x16x32_bf16(af, bfr, acc[f], 0, 0, 0);
        }
    }

    const int mrow = mBase + wid * 16 + lg * 4;
#pragma unroll
    for (int f = 0; f < 8; f++) {
        int n = nBase + f * 16 + lr;
#pragma unroll
        for (int r = 0; r < 4; r++)
            Y[(size_t)(mrow + r) * HW + n] = __float2bfloat16(acc[f][r]);
    }
}

// ---------------- Depthwise conv (radius R), bf16 in/out, vertical reuse ----
// Tile 64(h) x 32(w); thread (x = t&31, g = t>>5) computes 8 vertical outputs.
template <int R>
__global__ void dwconv_v2(const __hip_bfloat16* __restrict__ in,
                          const float* __restrict__ wdw,
                          const float* __restrict__ bias,
                          __hip_bfloat16* __restrict__ out) {
    constexpr int KS = 2 * R + 1;
    constexpr int LW = 32 + 2 * R;
    constexpr int LH = 64 + 2 * R;
    __shared__ float tile[LH][LW];
    const int c = blockIdx.y;
    const int x0 = (blockIdx.x & 7) * 32;
    const int y0 = (blockIdx.x >> 3) * 64;
    const __hip_bfloat16* src = in + (size_t)c * HW;

    float wreg[KS * KS];
#pragma unroll
    for (int i = 0; i < KS * KS; i++) wreg[i] = wdw[c * KS * KS + i];
    const float bval = bias[c];

    for (int idx = threadIdx.x; idx < LH * LW; idx += 256) {
        int ly = idx / LW, lx = idx - ly * LW;
        int gy = y0 + ly - R, gx = x0 + lx - R;
        float val = 0.f;
        if (gy >= 0 && gy < IMG && gx >= 0 && gx < IMG)
            val = b2f(*(const unsigned short*)(src + gy * IMG + gx));
        tile[ly][lx] = val;
    }
    __syncthreads();

    const int x = threadIdx.x & 31, g = threadIdx.x >> 5;
    float acc[8];
#pragma unroll
    for (int j = 0; j < 8; j++) acc[j] = bval;

#pragma unroll
    for (int kx = 0; kx < KS; kx++) {
#pragma unroll
        for (int yy = 0; yy < 7 + KS; yy++) {
            float vv = tile[g * 8 + yy][x + kx];
#pragma unroll
            for (int j = 0; j < 8; j++) {
                int ky = yy - j;
                if (ky >= 0 && ky < KS) acc[j] += vv * wreg[ky * KS + kx];
            }
        }
    }
    __hip_bfloat16* dst = out + (size_t)c * HW + (size_t)(y0 + g * 8) * IMG + x0 + x;
#pragma unroll
    for (int j = 0; j < 8; j++)
        dst[(size_t)j * IMG] = __float2bfloat16(acc[j]);
}

// ------------- Per-patch 8x8 circular convolution, bf16 in, f32 out ---------
__global__ void circconv3(const __hip_bfloat16* __restrict__ q,
                          const __hip_bfloat16* __restrict__ kin,
                          float* __restrict__ outp) {
    const int c = blockIdx.y;
    const int ph = blockIdx.x;
    const int pw = threadIdx.x & 31;
    const int i = threadIdx.x >> 5;
    const size_t base = (size_t)c * HW + (size_t)(ph * 8) * IMG + pw * 8;

    float acc[8];
#pragma unroll
    for (int j = 0; j < 8; j++) acc[j] = 0.f;

#pragma unroll
    for (int a = 0; a < 8; a++) {
        short8 qs = *(const short8*)(q + base + a * IMG);
        short8 ks = *(const short8*)(kin + base + ((i - a + 8) & 7) * IMG);
        float qv[8], kv[8];
#pragma unroll
        for (int e = 0; e < 8; e++) {
            qv[e] = b2f((unsigned short)qs[e]);
            kv[e] = b2f((unsigned short)ks[e]);
        }
#pragma unroll
        for (int b = 0; b < 8; b++)
#pragma unroll
            for (int j = 0; j < 8; j++)
                acc[j] += qv[b] * kv[(j - b + 8) & 7];
    }
    float* ob = outp + base + (size_t)i * IMG;
    *(float4*)ob = make_float4(acc[0], acc[1], acc[2], acc[3]);
    *(float4*)(ob + 4) = make_float4(acc[4], acc[5], acc[6], acc[7]);
}

// ------------- Fused: LayerNorm(ch)+affine, *v, proj GEMM + bias ------------
// s [192][HW] f32, v [192][HW] bf16, Wp [192][192] bf16, Y [192][HW] f32.
// grid (HW/128), block 256 = 4 waves; wave w owns output rows w*48..w*48+47.
__global__ __launch_bounds__(256, 2) void gemm_proj_ln(
    const __hip_bfloat16* __restrict__ Wp,
    const float* __restrict__ s,
    const __hip_bfloat16* __restrict__ v,
    const float* __restrict__ ln_w, const float* __restrict__ ln_b,
    const float* __restrict__ bias,
    float* __restrict__ Y) {
    __shared__ short Bs[128][200];
    __shared__ float red[2][2][128];
    __shared__ float muA[128], rsA[128];
    const int tid = threadIdx.x;
    const int p0 = blockIdx.x * 128;
    const int px = tid & 127, h = tid >> 7;

    // Phase A: read s once (f32), stats + stash raw bf16 pairs into Bs
    float sum = 0.f, sq = 0.f;
#pragma unroll 4
    for (int l = 0; l < 48; l++) {
        int c = h * 96 + l * 2;
        float a = s[(size_t)c * HW + p0 + px];
        float b = s[(size_t)(c + 1) * HW + p0 + px];
        sum += a + b;
        sq += a * a + b * b;
        unsigned pr = (unsigned)f2bu(a) | ((unsigned)f2bu(b) << 16);
        *(unsigned*)&Bs[px][c] = pr;
    }
    red[h][0][px] = sum;
    red[h][1][px] = sq;
    __syncthreads();
    if (tid < 128) {
        float sm = red[0][0][tid] + red[1][0][tid];
        float sQ = red[0][1][tid] + red[1][1][tid];
        float mu = sm * (1.f / 192.f);
        float var = sQ * (1.f / 192.f) - mu * mu;
        muA[tid] = mu;
        rsA[tid] = rsqrtf(var + 1e-5f);
    }
    __syncthreads();

    // Phase B: normalize in place, multiply by v
    const float mu = muA[px], rs = rsA[px];
#pragma unroll 4
    for (int l = 0; l < 48; l++) {
        int c = h * 96 + l * 2;
        unsigned pr = *(unsigned*)&Bs[px][c];
        float a = b2f((unsigned short)pr);
        float b = b2f((unsigned short)(pr >> 16));
        float va = b2f(*(const unsigned short*)(v + (size_t)c * HW + p0 + px));
        float vb = b2f(*(const unsigned short*)(v + (size_t)(c + 1) * HW + p0 + px));
        a = ((a - mu) * rs * ln_w[c] + ln_b[c]) * va;
        b = ((b - mu) * rs * ln_w[c + 1] + ln_b[c + 1]) * vb;
        *(unsigned*)&Bs[px][c] = (unsigned)f2bu(a) | ((unsigned)f2bu(b) << 16);
    }
    __syncthreads();

    // MFMA: A-fragments streamed from global (Wp is L2-resident)
    const int wid = tid >> 6, lane = tid & 63;
    const int lr = lane & 15, lg = lane >> 4;
    f32x4 acc[3][8];
#pragma unroll
    for (int mf = 0; mf < 3; mf++)
#pragma unroll
        for (int f = 0; f < 8; f++) acc[mf][f] = (f32x4){0.f, 0.f, 0.f, 0.f};

#pragma unroll
    for (int ks = 0; ks < 6; ks++) {
        short8 bfr[8];
#pragma unroll
        for (int f = 0; f < 8; f++)
            bfr[f] = *(const short8*)&Bs[f * 16 + lr][ks * 32 + lg * 8];
#pragma unroll
        for (int mf = 0; mf < 3; mf++) {
            int mrow = wid * 48 + mf * 16 + lr;
            short8 af = *(const short8*)(Wp + (size_t)mrow * 192 + ks * 32 + lg * 8);
#pragma unroll
            for (int f = 0; f < 8; f++)
                acc[mf][f] = __builtin_amdgcn_mfma_f32_16x16x32_bf16(af, bfr[f], acc[mf][f], 0, 0, 0);
        }
    }

#pragma unroll
    for (int mf = 0; mf < 3; mf++) {
        int m0 = wid * 48 + mf * 16 + lg * 4;
#pragma unroll
        for (int f = 0; f < 8; f++) {
            int n = p0 + f * 16 + lr;
#pragma unroll
            for (int r = 0; r < 4; r++)
                Y[(size_t)(m0 + r) * HW + n] = acc[mf][f][r] + bias[m0 + r];
        }
    }
}

extern "C" void kernel_launch(void* const* d_in, const int* in_sizes, int n_in,
                              void* d_out, int out_size, void* d_ws, size_t ws_size,
                              hipStream_t stream) {
    const float* x      = (const float*)d_in[0];
    const float* wq     = (const float*)d_in[1];
    const float* w_qdw  = (const float*)d_in[2];
    const float* b_qdw  = (const float*)d_in[3];
    const float* wkv    = (const float*)d_in[4];
    const float* w_kvdw = (const float*)d_in[5];
    const float* b_kvdw = (const float*)d_in[6];
    const float* ln_w   = (const float*)d_in[7];
    const float* ln_b   = (const float*)d_in[8];
    const float* w_proj = (const float*)d_in[9];
    const float* b_proj = (const float*)d_in[10];
    float* out = (float*)d_out;
    char* ws = (char*)d_ws;

    // ws map (bytes), total ~226.8 MB:
    __hip_bfloat16* qkv0  = (__hip_bfloat16*)(ws + 0);            // [576*HW] bf16
    __hip_bfloat16* qbuf  = (__hip_bfloat16*)(ws + 75497472);     // [192*HW] bf16
    __hip_bfloat16* kvbuf = (__hip_bfloat16*)(ws + 100663296);    // [384*HW] bf16
    float*          sbuf  = (float*)(ws + 150994944);             // [192*HW] f32
    __hip_bfloat16* xT    = (__hip_bfloat16*)(ws + 201326592);    // [HW*192] bf16
    __hip_bfloat16* Wqkv  = (__hip_bfloat16*)(ws + 226492416);    // [576*192]
    __hip_bfloat16* Wp    = Wqkv + 110592;                        // [192*192]

    pack_weights<<<576, 256, 0, stream>>>(wq, wkv, w_proj, Wqkv, Wp);

    for (int b = 0; b < 4; b++) {
        const float* xb = x + (size_t)b * CDIM * HW;
        transpose_cvt<<<dim3(HW / 32, 6), 256, 0, stream>>>(xb, xT);
        // fused q+kv 1x1 conv -> bf16
        gemm_bf16<<<dim3(9, HW / 128), 256, 0, stream>>>(Wqkv, xT, qkv0);
        // depthwise convs, bf16 in/out
        dwconv_v2<1><<<dim3(32, 192), 256, 0, stream>>>(qkv0, w_qdw, b_qdw, qbuf);
        dwconv_v2<3><<<dim3(32, 384), 256, 0, stream>>>(qkv0 + (size_t)192 * HW,
                                                        w_kvdw, b_kvdw, kvbuf);
        // per-patch circular convolution -> f32 sbuf
        circconv3<<<dim3(32, 192), 256, 0, stream>>>(qbuf, kvbuf, sbuf);
        // fused LN + *v + projection GEMM + bias -> out
        gemm_proj_ln<<<HW / 128, 256, 0, stream>>>(Wp, sbuf,
                                                   kvbuf + (size_t)192 * HW,
                                                   ln_w, ln_b, b_proj,
                                                   out + (size_t)b * CDIM * HW);
    }
}